// Round 4
// baseline (307.674 us; speedup 1.0000x reference)
//
#include <hip/hip_runtime.h>
#include <stdint.h>

// YOLO loss: S=7, B=2, C=80. preds cell = 90 f32, target cell = 85 f32.
// Output: 4 f32 scalars (coords, obj, noobj, classes), summed over 401408 cells.
//
// v5: wave-autonomous, barrier-free streaming pipeline.
//   Evidence (r3 post-mortem): v3 (reg staging) and v4 (global_load_lds DMA)
//   pinned at the SAME 115us / 2.44 TB/s blended despite different machinery.
//   Shared trait: barrier-ganged convoy consumption (full-drain vmcnt per
//   chunk, 2 s_barriers per iteration) -> ~34K cycles/iteration, waves ~95%
//   stalled on burst tail latency. v5: each WAVE owns its own chunk stream +
//   private LDS slice, counted vmcnt(6), NO barriers in the loop -> waves
//   slide past each other (RMSNorm-style TLP regime).

#define NPRED 90
#define NTGT  85
#define NCLS  80
#define CHW   8          // cells per wave-chunk
#define TPB   256
#define NBLK  1536       // 6 blocks/CU * 256 CUs (LDS-bound)

#define NTW4  (CHW * NTGT / 4)   // 170 float4 targ slab per chunk
#define NPW4  (CHW * NPRED / 4)  // 180 float4 preds slab per chunk

#define SBAR()    __builtin_amdgcn_sched_barrier(0)
#define WAITVM6() asm volatile("s_waitcnt vmcnt(6)" ::: "memory")
#define WAITVM0() asm volatile("s_waitcnt vmcnt(0)" ::: "memory")

__device__ __forceinline__ void load_lds16(const float4* g, float4* l) {
    // per-lane global src; LDS dest = wave-uniform base + lane*16
    __builtin_amdgcn_global_load_lds(
        (const __attribute__((address_space(1))) void*)g,
        (__attribute__((address_space(3))) void*)l,
        16, 0, 0);
}

// 3 DMA instrs cover 170 f4: [0,64), [64,128), [106,170) (overlap benign)
__device__ __forceinline__ void stage_targ(const float4* g, float4* l, int lane) {
    load_lds16(g + 0   + lane, l + 0);
    load_lds16(g + 64  + lane, l + 64);
    load_lds16(g + 106 + lane, l + 106);
}

__device__ __forceinline__ float sgnf(float x) {
    // matches jnp.sign: sign(0) == 0
    return (x > 0.0f) ? 1.0f : ((x < 0.0f) ? -1.0f : 0.0f);
}

__device__ __forceinline__ float iou_vs_target(
    float acx, float acy, float aw, float ah,
    float bx1, float by1, float bx2, float by2, float area_b)
{
    float ax1 = acx - aw * 0.5f, ay1 = acy - ah * 0.5f;
    float ax2 = acx + aw * 0.5f, ay2 = acy + ah * 0.5f;
    float iw = fmaxf(fminf(ax2, bx2) - fmaxf(ax1, bx1), 0.0f);
    float ih = fmaxf(fminf(ay2, by2) - fmaxf(ay1, by1), 0.0f);
    float inter = iw * ih;
    float area_a = (ax2 - ax1) * (ay2 - ay1);
    return inter / (area_a + area_b - inter);
}

__device__ __forceinline__ void pe(float v, int cl, int j, float obj,
    const float* __restrict__ tl, float* __restrict__ pbx, float& clsl)
{
    if (j < NCLS) {
        float d = fmaf(v, obj, -tl[cl * NTGT + j]);
        clsl = fmaf(d, d, clsl);
    } else {
        pbx[cl * 11 + (j - NCLS)] = v;   // box-field scatter (same-wave LDS)
    }
}

// quad q of the 180-f4 preds slab: f=4q, cl=f/90 in [0,8), j=f-90*cl (even)
__device__ __forceinline__ void proc_quad(float4 v, int q,
    const float* __restrict__ tl, float* __restrict__ pbx, float& clsl)
{
    int f  = 4 * q;
    int cl = f / NPRED;        // magic-mul
    int j  = f - cl * NPRED;
    if (j != 88) {
        float obj = tl[cl * NTGT + NCLS];
        pe(v.x, cl, j,     obj, tl, pbx, clsl);
        pe(v.y, cl, j + 1, obj, tl, pbx, clsl);
        pe(v.z, cl, j + 2, obj, tl, pbx, clsl);
        pe(v.w, cl, j + 3, obj, tl, pbx, clsl);
    } else {
        // x,y are box fields 8,9 of cl; z,w wrap to classes 0,1 of cl+1 (<8)
        pbx[cl * 11 + 8] = v.x;
        pbx[cl * 11 + 9] = v.y;
        float obj2 = tl[(cl + 1) * NTGT + NCLS];
        pe(v.z, cl + 1, 0, obj2, tl, pbx, clsl);
        pe(v.w, cl + 1, 1, obj2, tl, pbx, clsl);
    }
}

__global__ __launch_bounds__(TPB, 5) void yolo_loss_kernel(
    const float* __restrict__ preds, const float* __restrict__ targ,
    float* __restrict__ part, float* __restrict__ out,
    int n_cells, int mode)
{
    __shared__ float4 tring[4][2][NTW4];   // per-wave double-buffered targ slab
    __shared__ float  pbox[4][88];         // per-wave box scatter, stride 11
    __shared__ float  red[4][4];

    float coords = 0.0f, objl = 0.0f, noobjl = 0.0f, clsl = 0.0f;

    const int tid  = threadIdx.x;
    const int wave = tid >> 6;
    const int lane = tid & 63;
    const int nch  = n_cells / CHW;

    // contiguous chunk range per WAVE (autonomous streams, no block coupling)
    const long long wid = (long long)blockIdx.x * 4 + wave;
    const long long W   = (long long)gridDim.x * 4;
    const int s = (int)((wid * nch) / W);
    const int e = (int)(((wid + 1) * nch) / W);

    float* tl0 = (float*)&tring[wave][0][0];
    float* tl1 = (float*)&tring[wave][1][0];
    float* pbx = &pbox[wave][0];

    float4 pc0 = make_float4(0, 0, 0, 0), pc1 = pc0, pc2 = pc0;
    float4 pn0 = pc0, pn1 = pc0, pn2 = pc0;

    if (s < e) {
        // prologue: stage chunk s (targ->LDS buf[s&1], preds->regs)
        {
            const float4* tg = (const float4*)(targ  + (size_t)s * (CHW * NTGT));
            const float4* pg = (const float4*)(preds + (size_t)s * (CHW * NPRED));
            stage_targ(tg, (float4*)((s & 1) ? tl1 : tl0), lane);
            pc0 = pg[lane];
            pc1 = pg[64 + lane];
            pc2 = pg[116 + lane];   // f4 116..179; compute only lane>=12
        }

        for (int i = s; i < e; ++i) {
            const bool hn = (i + 1 < e);
            if (hn) {
                const float4* tgn = (const float4*)(targ  + (size_t)(i + 1) * (CHW * NTGT));
                const float4* pgn = (const float4*)(preds + (size_t)(i + 1) * (CHW * NPRED));
                stage_targ(tgn, (float4*)(((i + 1) & 1) ? tl1 : tl0), lane);
                pn0 = pgn[lane];
                pn1 = pgn[64 + lane];
                pn2 = pgn[116 + lane];
            }
            SBAR();                       // pin issue cluster above the wait
            if (hn) { WAITVM6(); }        // chunk i's 6 done; i+1's stay in flight
            else    { WAITVM0(); }
            SBAR();                       // rule #18: t_lds reads stay below wait

            const float* tl = (i & 1) ? tl1 : tl0;

            // ---- classes loss + box-field scatter (all 64 lanes) ----
            proc_quad(pc0, lane,      tl, pbx, clsl);
            proc_quad(pc1, 64 + lane, tl, pbx, clsl);
            if (lane >= 12)                       // f4 128..179 (116..127 dup)
                proc_quad(pc2, 116 + lane, tl, pbx, clsl);

            // ---- box losses: lanes 0..7, one cell each (same-wave LDS,
            //      compiler inserts lgkmcnt for pbox RAW; no barrier needed) ----
            if (lane < CHW) {
                const float* pb = pbx + lane * 11;        // p[80..89]
                const float* tc = tl + lane * NTGT + NCLS; // t[80..84]
                float obj = tc[0];
                float tcx = tc[1], tcy = tc[2], tw = tc[3], th = tc[4];
                float bx1 = tcx - tw * 0.5f, by1 = tcy - th * 0.5f;
                float bx2 = tcx + tw * 0.5f, by2 = tcy + th * 0.5f;
                float area_b = (bx2 - bx1) * (by2 - by1);

                // box1 = p[86..89], box2 = p[81..84]
                float iou1 = iou_vs_target(pb[6], pb[7], pb[8], pb[9],
                                           bx1, by1, bx2, by2, area_b);
                float iou2 = iou_vs_target(pb[1], pb[2], pb[3], pb[4],
                                           bx1, by1, bx2, by2, area_b);
                bool use2 = iou2 > iou1;  // argmax: tie -> box1

                float pcx = obj * (use2 ? pb[1] : pb[6]);
                float pw  = obj * (use2 ? pb[3] : pb[8]);
                float ph  = obj * (use2 ? pb[4] : pb[9]);

                // center loss uses ONLY cx (ref's [..., :-3] on a 4-vector)
                float dc = pcx - tcx;
                float dw = sgnf(pw) * sqrtf(fabsf(pw) + 1e-6f) - sqrtf(tw);
                float dh = sgnf(ph) * sqrtf(fabsf(ph) + 1e-6f) - sqrtf(th);
                coords = fmaf(dc, dc, coords);
                coords = fmaf(dw, dw, coords);
                coords = fmaf(dh, dh, coords);

                float obj_pred = use2 ? pb[0] : pb[5];  // p[80] : p[85]
                float e1 = fmaf(obj, obj_pred, -obj);
                objl = fmaf(e1, e1, objl);
                float e2 = fmaf(1.0f - obj, obj_pred, -obj);
                noobjl = fmaf(e2, e2, noobjl);
            }

            pc0 = pn0; pc1 = pn1; pc2 = pn2;   // rotate generations (static)
        }
    }

    // ---- remainder cells (none when n_cells % 8 == 0): scalar fallback ----
    for (int cell = nch * CHW + (int)(blockIdx.x * TPB + tid);
         cell < n_cells; cell += gridDim.x * TPB) {
        const float* p = preds + (size_t)cell * NPRED;
        const float* t = targ  + (size_t)cell * NTGT;
        float obj = t[NCLS];
        float cls = 0.0f;
        for (int k = 0; k < NCLS; ++k) {
            float d = fmaf(p[k], obj, -t[k]);
            cls = fmaf(d, d, cls);
        }
        clsl += cls;
        float tcx = t[81], tcy = t[82], tw = t[83], th = t[84];
        float bx1 = tcx - tw * 0.5f, by1 = tcy - th * 0.5f;
        float bx2 = tcx + tw * 0.5f, by2 = tcy + th * 0.5f;
        float area_b = (bx2 - bx1) * (by2 - by1);
        float iou1 = iou_vs_target(p[86], p[87], p[88], p[89],
                                   bx1, by1, bx2, by2, area_b);
        float iou2 = iou_vs_target(p[81], p[82], p[83], p[84],
                                   bx1, by1, bx2, by2, area_b);
        bool use2 = iou2 > iou1;
        float pcx = obj * (use2 ? p[81] : p[86]);
        float pw  = obj * (use2 ? p[83] : p[88]);
        float ph  = obj * (use2 ? p[84] : p[89]);
        float dc = pcx - tcx;
        float dw = sgnf(pw) * sqrtf(fabsf(pw) + 1e-6f) - sqrtf(tw);
        float dh = sgnf(ph) * sqrtf(fabsf(ph) + 1e-6f) - sqrtf(th);
        coords = fmaf(dc, dc, coords);
        coords = fmaf(dw, dw, coords);
        coords = fmaf(dh, dh, coords);
        float obj_pred = use2 ? p[80] : p[85];
        float e1 = fmaf(obj, obj_pred, -obj);
        objl = fmaf(e1, e1, objl);
        float e2 = fmaf(1.0f - obj, obj_pred, -obj);
        noobjl = fmaf(e2, e2, noobjl);
    }

    // ---- wave reduce (64 lanes) ----
    #pragma unroll
    for (int off = 32; off > 0; off >>= 1) {
        coords += __shfl_down(coords, off);
        objl   += __shfl_down(objl, off);
        noobjl += __shfl_down(noobjl, off);
        clsl   += __shfl_down(clsl, off);
    }

    __syncthreads();   // waves fully drained (vmcnt0 via last iter) before red[]
    if (lane == 0) {
        red[0][wave] = coords;
        red[1][wave] = objl;
        red[2][wave] = noobjl;
        red[3][wave] = clsl;
    }
    __syncthreads();
    if (tid == 0) {
        float c = red[0][0] + red[0][1] + red[0][2] + red[0][3];
        float o = red[1][0] + red[1][1] + red[1][2] + red[1][3];
        float n = red[2][0] + red[2][1] + red[2][2] + red[2][3];
        float k = red[3][0] + red[3][1] + red[3][2] + red[3][3];
        if (mode == 0) {
            int nb = gridDim.x;
            part[0 * nb + blockIdx.x] = c;
            part[1 * nb + blockIdx.x] = o;
            part[2 * nb + blockIdx.x] = n;
            part[3 * nb + blockIdx.x] = k;
        } else {
            atomicAdd(&out[0], 5.0f * c);
            atomicAdd(&out[1], o);
            atomicAdd(&out[2], 0.5f * n);
            atomicAdd(&out[3], k);
        }
    }
}

// one block, 4 waves: wave w reduces component w over nblk partials
__global__ __launch_bounds__(256) void yolo_reduce_kernel(
    const float* __restrict__ part, float* __restrict__ out, int nblk)
{
    int w = threadIdx.x >> 6;
    int lane = threadIdx.x & 63;
    float s = 0.0f;
    for (int i = lane; i < nblk; i += 64) s += part[w * nblk + i];
    #pragma unroll
    for (int off = 32; off > 0; off >>= 1) s += __shfl_down(s, off);
    if (lane == 0) {
        float scale = (w == 0) ? 5.0f : (w == 2) ? 0.5f : 1.0f;
        out[w] = s * scale;  // plain store overwrites poison
    }
}

extern "C" void kernel_launch(void* const* d_in, const int* in_sizes, int n_in,
                              void* d_out, int out_size, void* d_ws, size_t ws_size,
                              hipStream_t stream) {
    const float* preds = (const float*)d_in[0];
    const float* targ  = (const float*)d_in[1];
    float* out = (float*)d_out;

    int n_cells = in_sizes[0] / NPRED;  // 8192*7*7 = 401408

    bool use_ws = ws_size >= (size_t)(4 * NBLK) * sizeof(float);

    if (use_ws) {
        float* part = (float*)d_ws;
        hipLaunchKernelGGL(yolo_loss_kernel, dim3(NBLK), dim3(TPB), 0, stream,
                           preds, targ, part, out, n_cells, 0);
        hipLaunchKernelGGL(yolo_reduce_kernel, dim3(1), dim3(256), 0, stream,
                           part, out, NBLK);
        if (out_size > 4) {
            hipMemsetAsync(out + 4, 0, (size_t)(out_size - 4) * sizeof(float), stream);
        }
    } else {
        // fallback: contended-atomic path (d_out poisoned -> zero first)
        hipMemsetAsync(d_out, 0, (size_t)out_size * sizeof(float), stream);
        hipLaunchKernelGGL(yolo_loss_kernel, dim3(NBLK), dim3(TPB), 0, stream,
                           preds, targ, (float*)nullptr, out, n_cells, 1);
    }
}